// Round 20
// baseline (62.280 us; speedup 1.0000x reference)
//
#include <hip/hip_runtime.h>
#include <hip/hip_bf16.h>

#define NR  8192      // rows per view
#define M   16384     // 2*NR concatenated
#define TB  32768     // 256 rows * 128 B (one fp8 tile)
#define NTILES 2080   // upper triangle of 64x64 tiles

constexpr float INV_T   = 2.5f;                  // 1/0.4
constexpr float SCALE_S = 1.89914134f;           // sqrt(2.5*log2(e)); s^2=2.5*log2e
constexpr float E_REFL  = 12.182493960703473f;   // exp(2.5)
constexpr unsigned UNIT_E8M0 = 0x7F7F7F7Fu;      // e8m0 scale = 2^0 in all bytes

typedef int   i32x4 __attribute__((ext_vector_type(4)));
typedef int   i32x8 __attribute__((ext_vector_type(8)));
typedef float f32x4 __attribute__((ext_vector_type(4)));

typedef const __attribute__((address_space(1))) unsigned int* gas_u32;
typedef __attribute__((address_space(3))) unsigned int*       las_u32;

__device__ __forceinline__ float fexp2(float x) {
#if __has_builtin(__builtin_amdgcn_exp2f)
    return __builtin_amdgcn_exp2f(x);
#else
    return exp2f(x);
#endif
}

// ---------------------------------------------------------------------------
// Kernel 1: L2-normalize rows; store fp8(e4m3) Z = [z1n; z2n] PRE-SCALED by
// SCALE_S (so the MX-MFMA output is directly the exp2 argument); fp32 cross
// dot; zero the output scalar (final_kernel accumulates atomically).
// ---------------------------------------------------------------------------
__global__ __launch_bounds__(256) void norm_kernel(
    const float* __restrict__ outp, const float* __restrict__ augp,
    unsigned char* __restrict__ Zf8, float* __restrict__ posdot,
    float* __restrict__ outf)
{
    if (blockIdx.x == 0 && threadIdx.x == 0) outf[0] = 0.0f;

    const int w    = threadIdx.x >> 6;
    const int lane = threadIdx.x & 63;
    const int row  = blockIdx.x * 4 + w;

    float2 a = *(const float2*)(outp + row * 128 + lane * 2);
    float2 b = *(const float2*)(augp + row * 128 + lane * 2);

    float ssa = a.x * a.x + a.y * a.y;
    float ssb = b.x * b.x + b.y * b.y;
    #pragma unroll
    for (int m = 1; m < 64; m <<= 1) {
        ssa += __shfl_xor(ssa, m);
        ssb += __shfl_xor(ssb, m);
    }
    float inva = 1.0f / fmaxf(sqrtf(ssa), 1e-12f);
    float invb = 1.0f / fmaxf(sqrtf(ssb), 1e-12f);

    float xa0 = a.x * inva, xa1 = a.y * inva;   // unit-normalized (fp32)
    float xb0 = b.x * invb, xb1 = b.y * invb;

    unsigned int pa = __builtin_amdgcn_cvt_pk_fp8_f32(xa0 * SCALE_S, xa1 * SCALE_S, 0, false);
    unsigned int pb = __builtin_amdgcn_cvt_pk_fp8_f32(xb0 * SCALE_S, xb1 * SCALE_S, 0, false);
    *(unsigned short*)(Zf8 + (size_t)row * 128 + lane * 2)        = (unsigned short)pa;
    *(unsigned short*)(Zf8 + (size_t)(NR + row) * 128 + lane * 2) = (unsigned short)pb;

    float d = xa0 * xb0 + xa1 * xb1;   // positive-pair dot stays fp32-exact
    #pragma unroll
    for (int m = 1; m < 64; m <<= 1) d += __shfl_xor(d, m);
    if (lane == 0) posdot[row] = d;
}

// ---------------------------------------------------------------------------
// Kernel 2: SYMMETRIC partial sums of E = exp2(Zs Zs^T), ATOMIC-FREE.
// E symmetric -> only upper-triangular 256x256 tile pairs (a<=b): 2080
// equal-cost single-shot blocks.  Per block: Y tile (b) staged once via
// swizzled global_load_lds; afrag (a) direct from L2 (Z fp8 = 2 MB, fully
// XCD-L2-resident); ONE barrier; R14-proven bounded-unroll compute core.
// Row sums (rows of a, over b's 256 cols) -> registers -> rowLds -> ONE
// coalesced write rowpart[bid][256].  Col sums (rows of b, off-diag only)
// -> per-ct shuffle + ds_write into colLds[w][256] (each col hit exactly
// once) -> summed across waves at flush -> colpart[bid][256].
// NO atomics anywhere (R10's 2.7M cross-XCD atomicAdds = 30 MB HBM writes
// + 36 us stall was symmetry's killer).  A gather-reduce kernel assembles R.
// LDS 37888 B -> 4 blocks/CU; VGPR ~70 at launch_bounds(256,4) — no spill
// (R13/R17 lesson: bounded ct-quad unroll; check VGPR_Count first).
// ---------------------------------------------------------------------------
__global__ __launch_bounds__(256, 4) void gram_kernel(
    const unsigned char* __restrict__ Zf8,
    float* __restrict__ rowpart, float* __restrict__ colpart)
{
    __shared__ char  Ys[TB];            // 32 KB
    __shared__ float colLds[4][256];    // 4 KB (per-wave col partials)
    __shared__ float rowLds[256];       // 1 KB

    const int tid  = threadIdx.x;
    const int w    = tid >> 6;       // 0..3
    const int lane = tid & 63;
    const int l16  = lane & 15;
    const int lg   = lane >> 4;      // 0..3 (32-byte k-chunk / A-row group)

    // decode blockIdx.x -> (a,b), a<=b;  S(a) = 64a - a(a-1)/2  (R10-proven)
    const int bid = blockIdx.x;
    int a = (int)((129.0f - sqrtf(16641.0f - 8.0f * (float)bid)) * 0.5f);
    a = max(0, min(63, a));
    while (64 * a - (a * (a - 1)) / 2 > bid) --a;
    while (64 * (a + 1) - ((a + 1) * a) / 2 <= bid) ++a;
    const int b = a + (bid - (64 * a - (a * (a - 1)) / 2));

    const char* Zb = (const char*)Zf8;
    const char* Xg = Zb + (size_t)a * TB;
    const char* Yg = Zb + (size_t)b * TB;

    // stage Y tile: LDS[linear] = G[swz(linear)]; swz XORs byte bits 4..6
    // with row&7 (row = byte>>7 at 128 B/row) — involution, matches reads.
    #pragma unroll
    for (int it = 0; it < 8; ++it) {
        int off = w * 8192 + it * 1024 + lane * 16;
        int swz = off ^ (((off >> 7) & 7) << 4);
        __builtin_amdgcn_global_load_lds((gas_u32)(Yg + swz),
                                         (las_u32)(Ys + w * 8192 + it * 1024),
                                         16, 0, 0);
    }

    // A fragments: 64 rows per wave, full K=128 (32 B/lane), direct from L2
    i32x8 afrag[4];
    #pragma unroll
    for (int rt = 0; rt < 4; ++rt)
        afrag[rt] = *(const i32x8*)(Xg + (w * 64 + rt * 16 + l16) * 128 + lg * 32);

    __syncthreads();   // Y staged

    f32x4 rs[4];
    #pragma unroll
    for (int rt = 0; rt < 4; ++rt) rs[rt] = (f32x4){0.f, 0.f, 0.f, 0.f};
    const f32x4 zero4 = (f32x4){0.f, 0.f, 0.f, 0.f};

    // lane-constant swizzled LDS offsets; ct contributes bits >= 11 only
    const int key   = (l16 & 7) << 4;
    const int lbase = l16 * 128 + lg * 32;
    const int addrA = lbase ^ key;
    const int addrB = (lbase + 16) ^ key;

    #pragma unroll 1
    for (int cb = 0; cb < 4; ++cb) {
        #pragma unroll
        for (int ct = 0; ct < 4; ++ct) {
            const char* p = Ys + (cb * 4 + ct) * 2048;
            i32x8 b8;
            *(i32x4*)&b8       = *(const i32x4*)(p + addrA);
            *((i32x4*)&b8 + 1) = *(const i32x4*)(p + addrB);

            float cp = 0.0f;
            #pragma unroll
            for (int rt = 0; rt < 4; ++rt) {
                f32x4 d = __builtin_amdgcn_mfma_scale_f32_16x16x128_f8f6f4(
                    afrag[rt], b8, zero4,
                    0 /*fmtA=fp8*/, 0 /*fmtB=fp8*/,
                    0, UNIT_E8M0, 0, UNIT_E8M0);
                f32x4 e;
                e[0] = fexp2(d[0]); e[1] = fexp2(d[1]);
                e[2] = fexp2(d[2]); e[3] = fexp2(d[3]);
                rs[rt] += e;
                cp += (e[0] + e[1]) + (e[2] + e[3]);
            }
            // col sum for col (cb*4+ct)*16+l16: sum the 4 lg-groups (64 rows)
            cp += __shfl_xor(cp, 16);
            cp += __shfl_xor(cp, 32);
            if (lg == 0) colLds[w][(cb * 4 + ct) * 16 + l16] = cp;
        }
    }

    // row sums: reduce across the 16 lanes holding one row's columns
    #pragma unroll
    for (int rt = 0; rt < 4; ++rt)
        #pragma unroll
        for (int q = 0; q < 4; ++q) {
            float v = rs[rt][q];
            v += __shfl_xor(v, 1);  v += __shfl_xor(v, 2);
            v += __shfl_xor(v, 4);  v += __shfl_xor(v, 8);
            if (l16 == 0) rowLds[w * 64 + rt * 16 + lg * 4 + q] = v;
        }
    __syncthreads();

    // flush: one coalesced 1 KB write each, ZERO atomics
    rowpart[bid * 256 + tid] = rowLds[tid];
    if (a != b)
        colpart[bid * 256 + tid] = colLds[0][tid] + colLds[1][tid]
                                 + colLds[2][tid] + colLds[3][tid];
}

// ---------------------------------------------------------------------------
// Kernel 2b: gather-reduce partials -> R.  Row r (tile t=r>>8, i=r&255):
//   R[r] = sum_{b>=t} rowpart[S(t)+b-t][i] + sum_{a<t} colpart[S(a)+t-a][i]
// 64 terms/row; threads of a block share t -> every load is a coalesced
// 1 KB line.  16384 threads total.
// ---------------------------------------------------------------------------
__global__ __launch_bounds__(256) void reduce_kernel(
    const float* __restrict__ rowpart, const float* __restrict__ colpart,
    float* __restrict__ R)
{
    const int r = blockIdx.x * 256 + threadIdx.x;   // 0..16383
    const int t = r >> 8;
    const int i = r & 255;

    float s = 0.0f;
    const int St = 64 * t - (t * (t - 1)) / 2;
    for (int bb = t; bb < 64; ++bb)
        s += rowpart[(St + bb - t) * 256 + i];
    for (int aa = 0; aa < t; ++aa) {
        int bidA = 64 * aa - (aa * (aa - 1)) / 2 + (t - aa);
        s += colpart[bidA * 256 + i];
    }
    R[r] = s;
}

// ---------------------------------------------------------------------------
// Kernel 3: loss = mean_i [ -dot_i/tau + 0.5(log(R_i - E) + log(R_{NR+i} - E)) ]
// ---------------------------------------------------------------------------
__global__ __launch_bounds__(256) void final_kernel(
    const float* __restrict__ R, const float* __restrict__ posdot,
    float* __restrict__ outv)
{
    const int i = blockIdx.x * 256 + threadIdx.x;   // 0..8191
    float d1 = R[i]      - E_REFL;
    float d2 = R[NR + i] - E_REFL;
    float local = -posdot[i] * INV_T + 0.5f * (logf(d1) + logf(d2));

    #pragma unroll
    for (int m = 1; m < 64; m <<= 1) local += __shfl_xor(local, m);
    if ((threadIdx.x & 63) == 0)
        atomicAdd(outv, local * (1.0f / NR));
}

// ---------------------------------------------------------------------------
extern "C" void kernel_launch(void* const* d_in, const int* in_sizes, int n_in,
                              void* d_out, int out_size, void* d_ws, size_t ws_size,
                              hipStream_t stream) {
    const float* outp = (const float*)d_in[0];
    const float* augp = (const float*)d_in[1];

    char* ws = (char*)d_ws;
    unsigned char* Zf8 = (unsigned char*)ws;                    // 2 MB fp8
    float* R       = (float*)(ws + 2097152);                    // 64 KB
    float* posdot  = (float*)(ws + 2097152 + 65536);            // 32 KB
    float* rowpart = (float*)(ws + 2097152 + 65536 + 32768);    // 2.08 MB
    float* colpart = (float*)(ws + 2097152 + 65536 + 32768 + NTILES * 1024);
    float* outf    = (float*)d_out;

    hipLaunchKernelGGL(norm_kernel, dim3(2048), dim3(256), 0, stream,
                       outp, augp, Zf8, posdot, outf);

    hipLaunchKernelGGL(gram_kernel, dim3(NTILES), dim3(256), 0, stream,
                       Zf8, rowpart, colpart);

    hipLaunchKernelGGL(reduce_kernel, dim3(64), dim3(256), 0, stream,
                       rowpart, colpart, R);

    hipLaunchKernelGGL(final_kernel, dim3(32), dim3(256), 0, stream,
                       R, posdot, outf);
}

// Round 21
// 52.852 us; speedup vs baseline: 1.1784x; 1.1784x over previous
//
#include <hip/hip_runtime.h>
#include <hip/hip_bf16.h>

#define NR  8192      // rows per view
#define M   16384     // 2*NR concatenated
#define SUBB 16384    // 128 cols * 128 B (one fp8 Y sub-tile)

constexpr float INV_T   = 2.5f;                  // 1/0.4
constexpr float SCALE_S = 1.89914134f;           // sqrt(2.5*log2(e)); s^2=2.5*log2e
constexpr float E_REFL  = 12.182493960703473f;   // exp(2.5)
constexpr unsigned UNIT_E8M0 = 0x7F7F7F7Fu;      // e8m0 scale = 2^0 in all bytes

typedef int   i32x4 __attribute__((ext_vector_type(4)));
typedef int   i32x8 __attribute__((ext_vector_type(8)));
typedef float f32x4 __attribute__((ext_vector_type(4)));

typedef const __attribute__((address_space(1))) unsigned int* gas_u32;
typedef __attribute__((address_space(3))) unsigned int*       las_u32;

__device__ __forceinline__ float fexp2(float x) {
#if __has_builtin(__builtin_amdgcn_exp2f)
    return __builtin_amdgcn_exp2f(x);
#else
    return exp2f(x);
#endif
}

// Stage one 128-col (16 KB) fp8 sub-tile global->LDS with 256 threads:
// 4 x global_load_lds(16B) per thread. LDS dest linear; global src XOR-pre-
// swizzled (involution on byte bits 4..6 keyed by row&7 = bits 7..9) so
// swizzled 16B fragment reads are low-conflict.
__device__ __forceinline__ void stage_sub16(const char* __restrict__ gsrc,
                                            char* lds, int w, int lane) {
    #pragma unroll
    for (int it = 0; it < 4; ++it) {
        int off = w * 4096 + it * 1024 + lane * 16;
        int swz = off ^ (((off >> 7) & 7) << 4);
        __builtin_amdgcn_global_load_lds((gas_u32)(gsrc + swz),
                                         (las_u32)(lds + w * 4096 + it * 1024),
                                         16, 0, 0);
    }
}

// ---------------------------------------------------------------------------
// Kernel 1: L2-normalize rows; store fp8(e4m3) Z = [z1n; z2n] PRE-SCALED by
// SCALE_S (so the MX-MFMA output is directly the exp2 argument); fp32 cross
// dot; zero the rowsum array R AND the output scalar (final_kernel
// accumulates atomically -> re-zeroed every call for replay determinism).
// ---------------------------------------------------------------------------
__global__ __launch_bounds__(256) void norm_kernel(
    const float* __restrict__ outp, const float* __restrict__ augp,
    unsigned char* __restrict__ Zf8, float* __restrict__ R,
    float* __restrict__ posdot, float* __restrict__ outf)
{
    int gt = blockIdx.x * 256 + threadIdx.x;
    if (gt < M) R[gt] = 0.0f;
    if (gt == 0) outf[0] = 0.0f;

    const int w    = threadIdx.x >> 6;
    const int lane = threadIdx.x & 63;
    const int row  = blockIdx.x * 4 + w;

    float2 a = *(const float2*)(outp + row * 128 + lane * 2);
    float2 b = *(const float2*)(augp + row * 128 + lane * 2);

    float ssa = a.x * a.x + a.y * a.y;
    float ssb = b.x * b.x + b.y * b.y;
    #pragma unroll
    for (int m = 1; m < 64; m <<= 1) {
        ssa += __shfl_xor(ssa, m);
        ssb += __shfl_xor(ssb, m);
    }
    float inva = 1.0f / fmaxf(sqrtf(ssa), 1e-12f);
    float invb = 1.0f / fmaxf(sqrtf(ssb), 1e-12f);

    float xa0 = a.x * inva, xa1 = a.y * inva;   // unit-normalized (fp32)
    float xb0 = b.x * invb, xb1 = b.y * invb;

    unsigned int pa = __builtin_amdgcn_cvt_pk_fp8_f32(xa0 * SCALE_S, xa1 * SCALE_S, 0, false);
    unsigned int pb = __builtin_amdgcn_cvt_pk_fp8_f32(xb0 * SCALE_S, xb1 * SCALE_S, 0, false);
    *(unsigned short*)(Zf8 + (size_t)row * 128 + lane * 2)        = (unsigned short)pa;
    *(unsigned short*)(Zf8 + (size_t)(NR + row) * 128 + lane * 2) = (unsigned short)pb;

    float d = xa0 * xb0 + xa1 * xb1;   // positive-pair dot stays fp32-exact
    #pragma unroll
    for (int m = 1; m < 64; m <<= 1) d += __shfl_xor(d, m);
    if (lane == 0) posdot[row] = d;
}

// ---------------------------------------------------------------------------
// Kernel 2: row sums of exp2(Zs Zs^T) via MX-fp8 K=128 MFMA.
// FINAL STRUCTURE (R19, best measured 52.7 us total / ~47 us gram):
// Grid (32 col-chunks, 64 row-blocks) = 2048 blocks; launch_bounds(256,4)
// -> VGPR 44, no spill.  Wave owns 64 rows (afrag[4], full K=128,
// 32 B/lane, one-time L2 read).  Y chunk = 512 cols = 4 subtiles of 128
// cols (16 KB), double-buffered via global_load_lds (5 barriers/block).
// Per ct: 2 swizzled 16B LDS reads (lane-constant addresses; ct adds bits
// >= 11 only) -> b8 via subvector writes -> 4 MFMA (rt) -> 16 exp2 -> 16
// adds.  id%8 = ch%8 pins 4 chunks/XCD (Y 256 KB + Z 2 MB L2-resident).
// Falsified alternatives (measured): symmetry x3 (R3/R10/R20 — per-block
// overhead + partial plumbing eat the 2x FLOP saving), rt=8 both register
// regimes (R17 spill / R18 occupancy), counted-vmcnt ring (R7 neutral),
// single-shot (R14), self-paced waves (R15), direct-L2 B-operands (R8),
// 8-blocks/CU via launch_bounds (R11/R13 spill).  Wall ~= loose serial sum
// of MFMA (12.9) + VALU/exp2 (22) + LDS (~13) us — the practical floor for
// this decomposition at HIP level.
// ---------------------------------------------------------------------------
__global__ __launch_bounds__(256, 4) void gram_kernel(
    const unsigned char* __restrict__ Zf8, float* __restrict__ R)
{
    __shared__ char buf[2][SUBB];   // 32 KB

    const int tid  = threadIdx.x;
    const int w    = tid >> 6;       // 0..3
    const int lane = tid & 63;
    const int l16  = lane & 15;
    const int lg   = lane >> 4;      // 0..3 (32-byte k-chunk)
    const int ch   = blockIdx.x;     // 0..31 (512 cols each)
    const int rb   = blockIdx.y;     // 0..63 (256 rows each)

    const char* Zb = (const char*)Zf8;
    const char* Xg = Zb + (size_t)rb * 32768;     // 256 rows * 128 B
    const char* Yg = Zb + (size_t)ch * 65536;     // 512 cols * 128 B

    // A fragments: 64 rows per wave, full K=128 (32 B/lane), one-time read
    i32x8 afrag[4];
    #pragma unroll
    for (int rt = 0; rt < 4; ++rt)
        afrag[rt] = *(const i32x8*)(Xg + (w * 64 + rt * 16 + l16) * 128 + lg * 32);

    stage_sub16(Yg, buf[0], w, lane);
    __syncthreads();

    f32x4 rs[4];
    #pragma unroll
    for (int rt = 0; rt < 4; ++rt) rs[rt] = (f32x4){0.f, 0.f, 0.f, 0.f};
    const f32x4 zero4 = (f32x4){0.f, 0.f, 0.f, 0.f};

    // precomputed lane-constant LDS read offsets (ct adds bits >= 11 only)
    const int key   = (l16 & 7) << 4;
    const int lbase = l16 * 128 + lg * 32;
    const int addrA = lbase ^ key;
    const int addrB = (lbase + 16) ^ key;

    #pragma unroll 1
    for (int s = 0; s < 4; ++s) {
        if (s + 1 < 4)
            stage_sub16(Yg + (size_t)(s + 1) * SUBB, buf[(s + 1) & 1], w, lane);

        const char* cur = buf[s & 1];

        #pragma unroll 1
        for (int cb = 0; cb < 2; ++cb) {
            #pragma unroll
            for (int ct = 0; ct < 4; ++ct) {
                const char* p = cur + (cb * 4 + ct) * 2048;
                i32x8 b8;
                *(i32x4*)&b8       = *(const i32x4*)(p + addrA);
                *((i32x4*)&b8 + 1) = *(const i32x4*)(p + addrB);
                #pragma unroll
                for (int rt = 0; rt < 4; ++rt) {
                    f32x4 d = __builtin_amdgcn_mfma_scale_f32_16x16x128_f8f6f4(
                        afrag[rt], b8, zero4,
                        0 /*fmtA=fp8*/, 0 /*fmtB=fp8*/,
                        0, UNIT_E8M0, 0, UNIT_E8M0);
                    f32x4 e;
                    e[0] = fexp2(d[0]); e[1] = fexp2(d[1]);
                    e[2] = fexp2(d[2]); e[3] = fexp2(d[3]);
                    rs[rt] += e;
                }
            }
        }
        __syncthreads();   // stage(s+1) landed + all waves done with cur
    }

    // reduce row sums across the 16 lanes holding one row's columns
    #pragma unroll
    for (int rt = 0; rt < 4; ++rt)
        #pragma unroll
        for (int q = 0; q < 4; ++q) {
            float v = rs[rt][q];
            v += __shfl_xor(v, 1);  v += __shfl_xor(v, 2);
            v += __shfl_xor(v, 4);  v += __shfl_xor(v, 8);
            if (l16 == 0)
                atomicAdd(&R[rb * 256 + w * 64 + rt * 16 + lg * 4 + q], v);
        }
}

// ---------------------------------------------------------------------------
// Kernel 3: loss = mean_i [ -dot_i/tau + 0.5(log(R_i - E) + log(R_{NR+i} - E)) ]
// 32 blocks x 256 thr (1 row/thread), wave-shuffle reduce + one atomicAdd
// per wave into outf (zeroed by norm_kernel each call).
// ---------------------------------------------------------------------------
__global__ __launch_bounds__(256) void final_kernel(
    const float* __restrict__ R, const float* __restrict__ posdot,
    float* __restrict__ outv)
{
    const int i = blockIdx.x * 256 + threadIdx.x;   // 0..8191
    float d1 = R[i]      - E_REFL;
    float d2 = R[NR + i] - E_REFL;
    float local = -posdot[i] * INV_T + 0.5f * (logf(d1) + logf(d2));

    #pragma unroll
    for (int m = 1; m < 64; m <<= 1) local += __shfl_xor(local, m);
    if ((threadIdx.x & 63) == 0)
        atomicAdd(outv, local * (1.0f / NR));
}

// ---------------------------------------------------------------------------
extern "C" void kernel_launch(void* const* d_in, const int* in_sizes, int n_in,
                              void* d_out, int out_size, void* d_ws, size_t ws_size,
                              hipStream_t stream) {
    const float* outp = (const float*)d_in[0];
    const float* augp = (const float*)d_in[1];

    char* ws = (char*)d_ws;
    unsigned char* Zf8 = (unsigned char*)ws;                  // 2 MB fp8 [16384][128]
    float* R      = (float*)(ws + 2097152);                   // 16384 f32 row sums
    float* posdot = (float*)(ws + 2097152 + 65536);           // 8192 f32
    float* outf   = (float*)d_out;

    hipLaunchKernelGGL(norm_kernel, dim3(2048), dim3(256), 0, stream,
                       outp, augp, Zf8, R, posdot, outf);

    hipLaunchKernelGGL(gram_kernel, dim3(32, 64), dim3(256), 0, stream,
                       Zf8, R);

    hipLaunchKernelGGL(final_kernel, dim3(32), dim3(256), 0, stream,
                       R, posdot, outf);
}

// Round 22
// 44.449 us; speedup vs baseline: 1.4012x; 1.1891x over previous
//
#include <hip/hip_runtime.h>
#include <hip/hip_bf16.h>

#define NR  8192      // rows per view
#define M   16384     // 2*NR concatenated
#define SUBB 8192     // 128 cols * 64 B (one fp4 Y sub-tile)

constexpr float INV_T   = 2.5f;                  // 1/0.4
constexpr float SCALE_S = 1.89914134f;           // sqrt(2.5*log2(e)); s^2=2.5*log2e
constexpr float E_REFL  = 12.182493960703473f;   // exp(2.5)
constexpr unsigned SCALE_Q = 0x7C7C7C7Cu;        // e8m0 = 2^-3 in all bytes
constexpr float FOLD = 8.0f * SCALE_S;           // x8 fold, 2^-3 scale each side

typedef int   i32x4 __attribute__((ext_vector_type(4)));
typedef int   i32x8 __attribute__((ext_vector_type(8)));
typedef float f32x4 __attribute__((ext_vector_type(4)));

typedef const __attribute__((address_space(1))) unsigned int* gas_u32;
typedef __attribute__((address_space(3))) unsigned int*       las_u32;

__device__ __forceinline__ float fexp2(float x) {
#if __has_builtin(__builtin_amdgcn_exp2f)
    return __builtin_amdgcn_exp2f(x);
#else
    return exp2f(x);
#endif
}

// fp4 e2m1 encode (round-to-nearest): values {0,.5,1,1.5,2,3,4,6}, bit3=sign
__device__ __forceinline__ unsigned f4enc(float v) {
    unsigned s = v < 0.0f ? 8u : 0u;
    float m = fabsf(v);
    unsigned c = (m < 0.25f) ? 0u : (m < 0.75f) ? 1u : (m < 1.25f) ? 2u :
                 (m < 1.75f) ? 3u : (m < 2.5f)  ? 4u : (m < 3.5f)  ? 5u :
                 (m < 5.0f)  ? 6u : 7u;
    return s | c;
}

// Stage one 128-col (8 KB) fp4 sub-tile global->LDS with 256 threads:
// 2 x global_load_lds(16B) per thread.  LDS dest linear; global src XOR-pre-
// swizzled on the 16B-slot index (bits 5:4) with key (row&3)^((row>>2)&3)
// (row = off>>6 at 64 B/row) — involution; makes the 16-lane fragment reads
// exactly 2-way bank-aliased (free, m136).
__device__ __forceinline__ void stage_sub4(const char* __restrict__ gsrc,
                                           char* lds, int w, int lane) {
    #pragma unroll
    for (int it = 0; it < 2; ++it) {
        int off = w * 2048 + it * 1024 + lane * 16;
        int key = ((off >> 6) & 3) ^ ((off >> 8) & 3);
        int swz = off ^ (key << 4);
        __builtin_amdgcn_global_load_lds((gas_u32)(gsrc + swz),
                                         (las_u32)(lds + w * 2048 + it * 1024),
                                         16, 0, 0);
    }
}

// ---------------------------------------------------------------------------
// Kernel 1: L2-normalize rows; store fp4(e2m1) Z = [z1n; z2n] pre-folded by
// 8*SCALE_S (with 2^-3 e8m0 scales on both MFMA operands the product is
// exactly SCALE_S^2 * z.z = the exp2 argument); fp32 cross dot; zero R and
// the output scalar.
// ---------------------------------------------------------------------------
__global__ __launch_bounds__(256) void norm_kernel(
    const float* __restrict__ outp, const float* __restrict__ augp,
    unsigned char* __restrict__ Zf4, float* __restrict__ R,
    float* __restrict__ posdot, float* __restrict__ outf)
{
    int gt = blockIdx.x * 256 + threadIdx.x;
    if (gt < M) R[gt] = 0.0f;
    if (gt == 0) outf[0] = 0.0f;

    const int w    = threadIdx.x >> 6;
    const int lane = threadIdx.x & 63;
    const int row  = blockIdx.x * 4 + w;

    float2 a = *(const float2*)(outp + row * 128 + lane * 2);
    float2 b = *(const float2*)(augp + row * 128 + lane * 2);

    float ssa = a.x * a.x + a.y * a.y;
    float ssb = b.x * b.x + b.y * b.y;
    #pragma unroll
    for (int m = 1; m < 64; m <<= 1) {
        ssa += __shfl_xor(ssa, m);
        ssb += __shfl_xor(ssb, m);
    }
    float inva = 1.0f / fmaxf(sqrtf(ssa), 1e-12f);
    float invb = 1.0f / fmaxf(sqrtf(ssb), 1e-12f);

    float xa0 = a.x * inva, xa1 = a.y * inva;   // unit-normalized (fp32)
    float xb0 = b.x * invb, xb1 = b.y * invb;

    // fp4 pack: elements 2*lane (low nibble), 2*lane+1 (high nibble)
    unsigned ba = f4enc(xa0 * FOLD) | (f4enc(xa1 * FOLD) << 4);
    unsigned bb = f4enc(xb0 * FOLD) | (f4enc(xb1 * FOLD) << 4);
    Zf4[(size_t)row * 64 + lane]        = (unsigned char)ba;
    Zf4[(size_t)(NR + row) * 64 + lane] = (unsigned char)bb;

    float d = xa0 * xb0 + xa1 * xb1;   // positive-pair dot stays fp32-exact
    #pragma unroll
    for (int m = 1; m < 64; m <<= 1) d += __shfl_xor(d, m);
    if (lane == 0) posdot[row] = d;
}

// ---------------------------------------------------------------------------
// Kernel 2: row sums of exp2(Zs Zs^T) via MX-fp4 K=128 MFMA (fmt 4 = fp4,
// 2x the fp8 rate; half the LDS bytes).  R19 structure otherwise:
// grid (32 col-chunks, 64 row-blocks) = 2048 blocks; wave owns 64 rows
// (afrag[4]: full K=128 = 16 B/lane, zero-padded to the i32x8 operand);
// Y chunk = 512 cols = 4 subtiles of 128 cols (8 KB), double-buffered
// (16 KB LDS).  Per ct: ONE swizzled 16B LDS read -> b8 (lower half) ->
// 4 MFMA (rt) -> 16 exp2 -> 16 adds.  launch_bounds(256,3) gives the
// allocator ~170-reg headroom — no silent cap/spill (R11/R13/R17 lesson;
// verify VGPR_Count ~60-72 and FETCH ~8 MB first).
// id%8 = ch%8 pins 4 chunks/XCD (Z fp4 = 1 MB, fully L2-resident).
// ---------------------------------------------------------------------------
__global__ __launch_bounds__(256, 3) void gram_kernel(
    const unsigned char* __restrict__ Zf4, float* __restrict__ R)
{
    __shared__ char buf[2][SUBB];   // 16 KB

    const int tid  = threadIdx.x;
    const int w    = tid >> 6;       // 0..3
    const int lane = tid & 63;
    const int l16  = lane & 15;
    const int lg   = lane >> 4;      // 0..3 (16B k-chunk = 32 fp4 elems)
    const int ch   = blockIdx.x;     // 0..31 (512 cols each)
    const int rb   = blockIdx.y;     // 0..63 (256 rows each)

    const char* Zb = (const char*)Zf4;
    const char* Xg = Zb + (size_t)rb * 16384;     // 256 rows * 64 B
    const char* Yg = Zb + (size_t)ch * 32768;     // 512 cols * 64 B

    // A fragments: 64 rows per wave, full K=128 (16 B/lane), one-time read;
    // upper half of the f8f6f4 operand is unused for fp4 -> zero.
    i32x8 afrag[4];
    #pragma unroll
    for (int rt = 0; rt < 4; ++rt) {
        i32x4 lo = *(const i32x4*)(Xg + (w * 64 + rt * 16 + l16) * 64 + lg * 16);
        afrag[rt] = (i32x8){lo[0], lo[1], lo[2], lo[3], 0, 0, 0, 0};
    }

    stage_sub4(Yg, buf[0], w, lane);
    __syncthreads();

    f32x4 rs[4];
    #pragma unroll
    for (int rt = 0; rt < 4; ++rt) rs[rt] = (f32x4){0.f, 0.f, 0.f, 0.f};
    const f32x4 zero4 = (f32x4){0.f, 0.f, 0.f, 0.f};

    // lane-constant swizzled LDS read offset; ct adds bits >= 10 only and
    // the swizzle key (r&3)^((r>>2)&3) is invariant under r += 16.
    const int slot  = lg ^ (l16 & 3) ^ ((l16 >> 2) & 3);
    const int addrA = l16 * 64 + (slot << 4);

    #pragma unroll 1
    for (int s = 0; s < 4; ++s) {
        if (s + 1 < 4)
            stage_sub4(Yg + (size_t)(s + 1) * SUBB, buf[(s + 1) & 1], w, lane);

        const char* cur = buf[s & 1];

        #pragma unroll 1
        for (int cb = 0; cb < 2; ++cb) {
            #pragma unroll
            for (int ct = 0; ct < 4; ++ct) {
                const char* p = cur + (cb * 4 + ct) * 1024;
                i32x4 lo = *(const i32x4*)(p + addrA);
                i32x8 b8 = (i32x8){lo[0], lo[1], lo[2], lo[3], 0, 0, 0, 0};
                #pragma unroll
                for (int rt = 0; rt < 4; ++rt) {
                    f32x4 d = __builtin_amdgcn_mfma_scale_f32_16x16x128_f8f6f4(
                        afrag[rt], b8, zero4,
                        4 /*fmtA=fp4*/, 4 /*fmtB=fp4*/,
                        0, SCALE_Q, 0, SCALE_Q);
                    f32x4 e;
                    e[0] = fexp2(d[0]); e[1] = fexp2(d[1]);
                    e[2] = fexp2(d[2]); e[3] = fexp2(d[3]);
                    rs[rt] += e;
                }
            }
        }
        __syncthreads();   // stage(s+1) landed + all waves done with cur
    }

    // reduce row sums across the 16 lanes holding one row's columns
    #pragma unroll
    for (int rt = 0; rt < 4; ++rt)
        #pragma unroll
        for (int q = 0; q < 4; ++q) {
            float v = rs[rt][q];
            v += __shfl_xor(v, 1);  v += __shfl_xor(v, 2);
            v += __shfl_xor(v, 4);  v += __shfl_xor(v, 8);
            if (l16 == 0)
                atomicAdd(&R[rb * 256 + w * 64 + rt * 16 + lg * 4 + q], v);
        }
}

// ---------------------------------------------------------------------------
// Kernel 3: loss = mean_i [ -dot_i/tau + 0.5(log(R_i - E) + log(R_{NR+i} - E)) ]
// 32 blocks x 256 thr, wave-shuffle reduce + one atomicAdd per wave.
// ---------------------------------------------------------------------------
__global__ __launch_bounds__(256) void final_kernel(
    const float* __restrict__ R, const float* __restrict__ posdot,
    float* __restrict__ outv)
{
    const int i = blockIdx.x * 256 + threadIdx.x;   // 0..8191
    float d1 = R[i]      - E_REFL;
    float d2 = R[NR + i] - E_REFL;
    float local = -posdot[i] * INV_T + 0.5f * (logf(d1) + logf(d2));

    #pragma unroll
    for (int m = 1; m < 64; m <<= 1) local += __shfl_xor(local, m);
    if ((threadIdx.x & 63) == 0)
        atomicAdd(outv, local * (1.0f / NR));
}

// ---------------------------------------------------------------------------
extern "C" void kernel_launch(void* const* d_in, const int* in_sizes, int n_in,
                              void* d_out, int out_size, void* d_ws, size_t ws_size,
                              hipStream_t stream) {
    const float* outp = (const float*)d_in[0];
    const float* augp = (const float*)d_in[1];

    char* ws = (char*)d_ws;
    unsigned char* Zf4 = (unsigned char*)ws;                  // 1 MB fp4 [16384][64B]
    float* R      = (float*)(ws + 1048576);                   // 16384 f32 row sums
    float* posdot = (float*)(ws + 1048576 + 65536);           // 8192 f32
    float* outf   = (float*)d_out;

    hipLaunchKernelGGL(norm_kernel, dim3(2048), dim3(256), 0, stream,
                       outp, augp, Zf4, R, posdot, outf);

    hipLaunchKernelGGL(gram_kernel, dim3(32, 64), dim3(256), 0, stream,
                       Zf4, R);

    hipLaunchKernelGGL(final_kernel, dim3(32), dim3(256), 0, stream,
                       R, posdot, outf);
}